// Round 13
// baseline (423.739 us; speedup 1.0000x reference)
//
#include <hip/hip_runtime.h>
#include <stdint.h>

#define BB 512
#define NN 8192
#define KK 16
#define HH 16
#define NBLK 1024

typedef _Float16 f16;
typedef _Float16 f16x4 __attribute__((ext_vector_type(4)));
typedef float f32x4 __attribute__((ext_vector_type(4)));

// ---------------------------------------------------------------------------
// Single-use device-wide barrier (all NBLK blocks resident via cooperative
// launch).  counter/flag live in d_ws, zeroed by hipMemsetAsync in-graph
// before each kernel run.  Release: __threadfence + device-scope atomicAdd;
// acquire: flag spin (s_sleep) + reader-side __threadfence.
// ---------------------------------------------------------------------------
__device__ __forceinline__ void dev_barrier(uint32_t* cnt, uint32_t* flag) {
    __syncthreads();
    if (threadIdx.x == 0) {
        __threadfence();  // make this block's global stores visible
        const uint32_t prev = __hip_atomic_fetch_add(
            cnt, 1u, __ATOMIC_ACQ_REL, __HIP_MEMORY_SCOPE_AGENT);
        if (prev + 1u == (uint32_t)NBLK) {
            __hip_atomic_store(flag, 1u, __ATOMIC_RELEASE,
                               __HIP_MEMORY_SCOPE_AGENT);
        } else {
            uint32_t v;
            do {
                __builtin_amdgcn_s_sleep(2);
                v = __hip_atomic_load(flag, __ATOMIC_ACQUIRE,
                                      __HIP_MEMORY_SCOPE_AGENT);
            } while (v == 0u);
        }
    }
    __syncthreads();
    __threadfence();  // reader-side: discard any stale cached lines
}

// ---------------------------------------------------------------------------
// Fused kernel, cooperative, grid = 1024 x 512thr (4 blocks/CU, 1 generation).
// Phase 1 (blocks 0..255): pack signs of x into xpT[j*16+w] (512 KB);
//   coalesced reads, LDS-staged contiguous 2 KB write (pstage aliases tile).
// All blocks concurrently: issue xpT-independent prologue loads (W1 strided
//   f32 -> f16 A-frags, neighs, b1, W2, b2).
// dev_barrier
// Phase 2: block = 16n x 256b, wave = 2n x 256b; R10-proven loop: sign-word
//   gather (uint2/lane), wave-private wbuf, B-frag = bit -> +-1.0f16,
//   mfma_f32_16x16x16_f16, 8-op relu-dot -> zbuf (rows padded to 6 floats:
//   conflict-free dense read), per-4-tile dense pass (64 lanes = 64 outputs,
//   rcpf(1+expf)).  Output transpose via tile[256][20]; full-line stores.
// LDS: wbuf 5K + zbuf 12K + tile 20K = 37.9KB -> 4 blocks/CU, 8 waves/SIMD.
// ---------------------------------------------------------------------------
__global__ __launch_bounds__(512, 8) void fused_kernel(
    const float* __restrict__ x, const int* __restrict__ neighs,
    const float* __restrict__ W1, const float* __restrict__ b1,
    const float* __restrict__ W2, const float* __restrict__ b2,
    uint32_t* __restrict__ xpT, uint32_t* __restrict__ bar,
    float* __restrict__ out) {
    __shared__ __align__(16) uint32_t wbuf[8][8 * 20];  // [wave][w*20+k]
    __shared__ __align__(16) float zbuf[8][64][6];      // padded rows
    __shared__ __align__(16) float tile[256 * 20];      // [b_local][n_local]

    const int tid = threadIdx.x;
    const int bid = blockIdx.x;
    const int wv  = tid >> 6;        // 0..7
    const int l   = tid & 63;
    const int l15 = l & 15;
    const int lg  = l >> 4;          // 0..3
    const int n0  = (bid >> 1) * 16;
    const int half = bid & 1;
    const int b0  = half * 256;
    const int w0  = half * 8;

    const int nA = n0 + wv * 2;
    const int nB = nA + 1;

    // ---- prologue loads independent of xpT (issue before barrier) ----
    const int j0g = neighs[nA * KK + l15];   // 64B broadcast
    const int j1g = neighs[nB * KK + l15];
    const float* W1nA = W1 + (size_t)nA * (KK * HH) + lg * 4 * HH + l15;
    const float* W1nB = W1 + (size_t)nB * (KK * HH) + lg * 4 * HH + l15;
    const float a0 = W1nA[0 * HH], a1 = W1nA[1 * HH];
    const float a2 = W1nA[2 * HH], a3 = W1nA[3 * HH];
    const float a4 = W1nB[0 * HH], a5 = W1nB[1 * HH];
    const float a6 = W1nB[2 * HH], a7 = W1nB[3 * HH];
    const float4 b1v0 = *(const float4*)(b1 + (size_t)nA * HH + lg * 4);
    const float4 b1v1 = *(const float4*)(b1 + (size_t)nB * HH + lg * 4);
    const float4 w2v0 = *(const float4*)(W2 + (size_t)nA * HH + lg * 4);
    const float4 w2v1 = *(const float4*)(W2 + (size_t)nB * HH + lg * 4);
    const float b2n0 = b2[nA];
    const float b2n1 = b2[nB];

    // ---- phase 1: pack (blocks 0..255), pstage aliases tile ----
    if (bid < 256) {
        uint32_t* pstage = (uint32_t*)tile;   // 32*17 words
        const int j0 = bid * 32;
        const int jl = tid & 31;   // 32 consecutive j -> coalesced reads
        const int wq = tid >> 5;   // 0..15
        uint32_t word = 0u;
#pragma unroll
        for (int i = 0; i < 32; ++i)
            word |= (x[(size_t)(wq * 32 + i) * NN + j0 + jl] > 0.0f ? 1u : 0u)
                    << i;
        pstage[jl * 17 + wq] = word;
        __syncthreads();
        xpT[(size_t)j0 * 16 + tid] = pstage[(tid >> 4) * 17 + (tid & 15)];
    }

    // ---- device-wide barrier: xpT complete ----
    dev_barrier(bar, bar + 1);

    // ---- phase 2: gathers + MFMA loop (R10 structure) ----
    const uint2 g0 = *(const uint2*)&xpT[(size_t)j0g * 16 + w0 + lg * 2];
    const uint2 g1 = *(const uint2*)&xpT[(size_t)j1g * 16 + w0 + lg * 2];

    const f16x4 aA = {(f16)a0, (f16)a1, (f16)a2, (f16)a3};
    const f16x4 aB = {(f16)a4, (f16)a5, (f16)a6, (f16)a7};
    const f32x4 cinit0 = {b1v0.x, b1v0.y, b1v0.z, b1v0.w};
    const f32x4 cinit1 = {b1v1.x, b1v1.y, b1v1.z, b1v1.w};

#pragma unroll
    for (int ni = 0; ni < 2; ++ni) {
        const uint2 g = ni ? g1 : g0;
        const f16x4 a = ni ? aB : aA;
        const f32x4 cinit = ni ? cinit1 : cinit0;
        const float4 w2v = ni ? w2v1 : w2v0;
        const float b2n  = ni ? b2n1 : b2n0;
        const int nloc = wv * 2 + ni;

        // stage this ni's sign words (wave-private, lgkmcnt-ordered)
        wbuf[wv][(2 * lg) * 20 + l15]     = g.x;
        wbuf[wv][(2 * lg + 1) * 20 + l15] = g.y;

#pragma unroll
        for (int g4 = 0; g4 < 4; ++g4) {   // 4 groups x 4 tiles of 16 b
#pragma unroll
            for (int t = 0; t < 4; ++t) {
                const int tb = g4 * 4 + t;
                const int wg = tb >> 1;
                const uint4 wk = *(const uint4*)&wbuf[wv][wg * 20 + lg * 4];
                const int pos = (tb & 1) * 16 + l15;
                // bit=1 -> +1.0f16 (0x3C00), bit=0 -> -1.0f16 (0xBC00)
                const uint32_t d0 = 0xBC00BC00u ^ (((wk.x >> pos) & 1u) << 15) ^
                                    ((wk.y >> pos) << 31);
                const uint32_t d1 = 0xBC00BC00u ^ (((wk.z >> pos) & 1u) << 15) ^
                                    ((wk.w >> pos) << 31);
                uint2 bdu; bdu.x = d0; bdu.y = d1;
                const f16x4 bfr = __builtin_bit_cast(f16x4, bdu);

                const f32x4 acc = __builtin_amdgcn_mfma_f32_16x16x16f16(
                    a, bfr, cinit, 0, 0, 0);

                const float zp =
                    fmaf(fmaxf(acc[0], 0.f), w2v.x,
                    fmaf(fmaxf(acc[1], 0.f), w2v.y,
                    fmaf(fmaxf(acc[2], 0.f), w2v.z,
                         fmaxf(acc[3], 0.f) * w2v.w)));
                zbuf[wv][t * 16 + l15][lg] = zp;
            }
            // dense pass: 64 lanes = 64 outputs of this 4-tile group
            const float z = (zbuf[wv][l][0] + zbuf[wv][l][1]) +
                            (zbuf[wv][l][2] + zbuf[wv][l][3]) + b2n;
            const float r = __builtin_amdgcn_rcpf(1.0f + __expf(-z));
            tile[(g4 * 64 + l) * 20 + nloc] = r;
        }
    }
    __syncthreads();

    // full-line stores: 4 lanes cover one 64B row of out[b][n0..n0+15]
#pragma unroll
    for (int p = 0; p < 2; ++p) {
        const int row = (tid >> 2) + p * 128;
        const int c   = (tid & 3) * 4;
        const float4 v = *(const float4*)&tile[row * 20 + c];
        *(float4*)(out + (size_t)(b0 + row) * NN + n0 + c) = v;
    }
}

// ===========================================================================
// Fallback path (R10): separate pack + mfma kernels (used only if the
// cooperative launch is rejected).  Identical math.
// ===========================================================================
__global__ __launch_bounds__(512) void pack_kernel(const float* __restrict__ x,
                                                   uint32_t* __restrict__ xpT) {
    __shared__ uint32_t pstage[32 * 17];
    const int tid = threadIdx.x;
    const int j0  = blockIdx.x * 32;
    const int jl  = tid & 31;
    const int wq  = tid >> 5;
    uint32_t word = 0u;
#pragma unroll
    for (int i = 0; i < 32; ++i)
        word |= (x[(size_t)(wq * 32 + i) * NN + j0 + jl] > 0.0f ? 1u : 0u) << i;
    pstage[jl * 17 + wq] = word;
    __syncthreads();
    xpT[(size_t)j0 * 16 + tid] = pstage[(tid >> 4) * 17 + (tid & 15)];
}

__global__ __launch_bounds__(512, 8) void mfma_kernel(
    const uint32_t* __restrict__ xpT, const float* __restrict__ W1,
    const int* __restrict__ neighs, const float* __restrict__ b1,
    const float* __restrict__ W2, const float* __restrict__ b2,
    float* __restrict__ out) {
    __shared__ __align__(16) uint32_t wbuf[8][8 * 20];
    __shared__ __align__(16) float zbuf[8][64][6];
    __shared__ __align__(16) float tile[256 * 12];

    const int tid = threadIdx.x;
    const int wv  = tid >> 6;
    const int l   = tid & 63;
    const int l15 = l & 15;
    const int lg  = l >> 4;
    const int n0  = blockIdx.x * 8;
    const int b0  = blockIdx.y * 256;
    const int w0  = blockIdx.y * 8;
    const int n   = n0 + wv;

    const int j = neighs[n * KK + l15];
    const uint2 g = *(const uint2*)&xpT[(size_t)j * 16 + w0 + lg * 2];
    const float* W1n = W1 + (size_t)n * (KK * HH) + lg * 4 * HH + l15;
    const float a0 = W1n[0 * HH], a1 = W1n[1 * HH];
    const float a2 = W1n[2 * HH], a3 = W1n[3 * HH];
    const float4 b1v = *(const float4*)(b1 + (size_t)n * HH + lg * 4);
    const float4 w2v = *(const float4*)(W2 + (size_t)n * HH + lg * 4);
    const float b2n = b2[n];

    const f16x4 a = {(f16)a0, (f16)a1, (f16)a2, (f16)a3};
    const f32x4 cinit = {b1v.x, b1v.y, b1v.z, b1v.w};

    wbuf[wv][(2 * lg) * 20 + l15]     = g.x;
    wbuf[wv][(2 * lg + 1) * 20 + l15] = g.y;

#pragma unroll
    for (int g4 = 0; g4 < 4; ++g4) {
#pragma unroll
        for (int t = 0; t < 4; ++t) {
            const int tb = g4 * 4 + t;
            const int wg = tb >> 1;
            const uint4 wk = *(const uint4*)&wbuf[wv][wg * 20 + lg * 4];
            const int pos = (tb & 1) * 16 + l15;
            const uint32_t d0 = 0xBC00BC00u ^ (((wk.x >> pos) & 1u) << 15) ^
                                ((wk.y >> pos) << 31);
            const uint32_t d1 = 0xBC00BC00u ^ (((wk.z >> pos) & 1u) << 15) ^
                                ((wk.w >> pos) << 31);
            uint2 bdu; bdu.x = d0; bdu.y = d1;
            const f16x4 bfr = __builtin_bit_cast(f16x4, bdu);
            const f32x4 acc = __builtin_amdgcn_mfma_f32_16x16x16f16(
                a, bfr, cinit, 0, 0, 0);
            const float zp =
                fmaf(fmaxf(acc[0], 0.f), w2v.x,
                fmaf(fmaxf(acc[1], 0.f), w2v.y,
                fmaf(fmaxf(acc[2], 0.f), w2v.z,
                     fmaxf(acc[3], 0.f) * w2v.w)));
            zbuf[wv][t * 16 + l15][lg] = zp;
        }
        const float z = (zbuf[wv][l][0] + zbuf[wv][l][1]) +
                        (zbuf[wv][l][2] + zbuf[wv][l][3]) + b2n;
        const float r = __builtin_amdgcn_rcpf(1.0f + __expf(-z));
        tile[(g4 * 64 + l) * 12 + wv] = r;
    }
    __syncthreads();

    const int row = tid >> 1;
    const int c   = (tid & 1) * 4;
    const float4 v = *(const float4*)&tile[row * 12 + c];
    *(float4*)(out + (size_t)(b0 + row) * NN + n0 + c) = v;
}

__global__ __launch_bounds__(512) void scalar_kernel(
    const float* __restrict__ x, const int* __restrict__ neighs,
    const float* __restrict__ W1, const float* __restrict__ b1,
    const float* __restrict__ W2, const float* __restrict__ b2,
    float* __restrict__ outp) {
    const int n = blockIdx.x;
    const int b = threadIdx.x;
    const int* nb = neighs + n * KK;
    const float* W1n = W1 + (size_t)n * KK * HH;
    const float* b1n = b1 + (size_t)n * HH;
    const float* W2n = W2 + (size_t)n * HH;

    float s[KK];
#pragma unroll
    for (int k = 0; k < KK; ++k) s[k] = x[(size_t)b * NN + nb[k]];

    float acc[HH];
#pragma unroll
    for (int h = 0; h < HH; ++h) acc[h] = b1n[h];
#pragma unroll
    for (int k = 0; k < KK; ++k)
#pragma unroll
        for (int h = 0; h < HH; ++h)
            acc[h] = fmaf(s[k], W1n[k * HH + h], acc[h]);

    float z = b2[n];
#pragma unroll
    for (int h = 0; h < HH; ++h)
        z = fmaf(fmaxf(acc[h], 0.0f), W2n[h], z);
    outp[(size_t)b * NN + n] = 1.0f / (1.0f + __expf(-z));
}

extern "C" void kernel_launch(void* const* d_in, const int* in_sizes, int n_in,
                              void* d_out, int out_size, void* d_ws, size_t ws_size,
                              hipStream_t stream) {
    const float* x      = (const float*)d_in[0];
    const int*   neighs = (const int*)d_in[1];
    const float* W1     = (const float*)d_in[2];
    const float* b1     = (const float*)d_in[3];
    const float* W2     = (const float*)d_in[4];
    const float* b2     = (const float*)d_in[5];
    float* out = (float*)d_out;

    const size_t pack_bytes = (size_t)NN * 16 * sizeof(uint32_t);  // 512 KB

    if (ws_size >= pack_bytes + 64) {
        uint32_t* xpT = (uint32_t*)d_ws;
        uint32_t* bar = (uint32_t*)((char*)d_ws + pack_bytes);  // 2 words

        hipMemsetAsync(bar, 0, 8, stream);
        void* kargs[] = {(void*)&x, (void*)&neighs, (void*)&W1, (void*)&b1,
                         (void*)&W2, (void*)&b2, (void*)&xpT, (void*)&bar,
                         (void*)&out};
        hipError_t e = hipLaunchCooperativeKernel(
            (const void*)fused_kernel, dim3(NBLK), dim3(512), kargs, 0, stream);
        if (e != hipSuccess) {
            pack_kernel<<<NN / 32, 512, 0, stream>>>(x, xpT);
            mfma_kernel<<<dim3(NN / 8, BB / 256), 512, 0, stream>>>(
                xpT, W1, neighs, b1, W2, b2, out);
        }
    } else {
        scalar_kernel<<<NN, BB, 0, stream>>>(x, neighs, W1, b1, W2, b2, out);
    }
}

// Round 14
// 213.974 us; speedup vs baseline: 1.9803x; 1.9803x over previous
//
#include <hip/hip_runtime.h>
#include <stdint.h>

#define BB 512
#define NN 8192
#define KK 16
#define HH 16
#define NBLK 1024
#define NPACK 256

typedef _Float16 f16;
typedef _Float16 f16x4 __attribute__((ext_vector_type(4)));
typedef float f32x4 __attribute__((ext_vector_type(4)));

// ---------------------------------------------------------------------------
// Fused kernel, cooperative, grid = 1024 x 512thr (4 blocks/CU, 1 generation).
// Phase 1 (blocks 0..255): pack signs of x into xpT[j*16+w] (512 KB).
// Barrier: 256 arrivals (device-scope atomicAdd after per-thread threadfence);
//   waiters poll the flag with RELAXED atomic-RMW (atomicAdd(flag,0)) --
//   executes at the coherence point, NO cache invalidation per poll (the
//   acquire-load polling of R8/R13 caused invalidate storms -> 400us).
//   One __threadfence per block after the flag flips.
// Phase 2: block = 16n x 256b, wave = 2n x 256b; R10-proven loop: sign-word
//   gather (uint2/lane), wave-private wbuf, B-frag = bit -> +-1.0f16,
//   mfma_f32_16x16x16_f16, 8-op relu-dot -> zbuf (rows padded to 6 floats),
//   per-4-tile dense pass (64 lanes = 64 outputs, rcpf(1+expf)).
//   Output transpose via tile[256][20]; full-64B-line stores.
// LDS: wbuf 5K + zbuf 12K + tile 20K = 37.9KB -> 4 blocks/CU, 8 waves/SIMD.
// ---------------------------------------------------------------------------
__global__ __launch_bounds__(512, 8) void fused_kernel(
    const float* __restrict__ x, const int* __restrict__ neighs,
    const float* __restrict__ W1, const float* __restrict__ b1,
    const float* __restrict__ W2, const float* __restrict__ b2,
    uint32_t* __restrict__ xpT, uint32_t* __restrict__ bar,
    float* __restrict__ out) {
    __shared__ __align__(16) uint32_t wbuf[8][8 * 20];  // [wave][w*20+k]
    __shared__ __align__(16) float zbuf[8][64][6];      // padded rows
    __shared__ __align__(16) float tile[256 * 20];      // [b_local][n_local]

    const int tid = threadIdx.x;
    const int bid = blockIdx.x;
    const int wv  = tid >> 6;        // 0..7
    const int l   = tid & 63;
    const int l15 = l & 15;
    const int lg  = l >> 4;          // 0..3
    const int n0  = (bid >> 1) * 16;
    const int half = bid & 1;
    const int b0  = half * 256;
    const int w0  = half * 8;

    const int nA = n0 + wv * 2;
    const int nB = nA + 1;

    // ---- prologue loads independent of xpT (issue before barrier) ----
    const int j0g = neighs[nA * KK + l15];   // 64B broadcast
    const int j1g = neighs[nB * KK + l15];
    const float* W1nA = W1 + (size_t)nA * (KK * HH) + lg * 4 * HH + l15;
    const float* W1nB = W1 + (size_t)nB * (KK * HH) + lg * 4 * HH + l15;
    const float a0 = W1nA[0 * HH], a1 = W1nA[1 * HH];
    const float a2 = W1nA[2 * HH], a3 = W1nA[3 * HH];
    const float a4 = W1nB[0 * HH], a5 = W1nB[1 * HH];
    const float a6 = W1nB[2 * HH], a7 = W1nB[3 * HH];
    const float4 b1v0 = *(const float4*)(b1 + (size_t)nA * HH + lg * 4);
    const float4 b1v1 = *(const float4*)(b1 + (size_t)nB * HH + lg * 4);
    const float4 w2v0 = *(const float4*)(W2 + (size_t)nA * HH + lg * 4);
    const float4 w2v1 = *(const float4*)(W2 + (size_t)nB * HH + lg * 4);
    const float b2n0 = b2[nA];
    const float b2n1 = b2[nB];

    // ---- phase 1: pack (blocks 0..255), pstage aliases tile ----
    if (bid < NPACK) {
        uint32_t* pstage = (uint32_t*)tile;   // 32*17 words
        const int j0 = bid * 32;
        const int jl = tid & 31;   // 32 consecutive j -> coalesced reads
        const int wq = tid >> 5;   // 0..15
        uint32_t word = 0u;
#pragma unroll
        for (int i = 0; i < 32; ++i)
            word |= (x[(size_t)(wq * 32 + i) * NN + j0 + jl] > 0.0f ? 1u : 0u)
                    << i;
        pstage[jl * 17 + wq] = word;
        __syncthreads();
        xpT[(size_t)j0 * 16 + tid] = pstage[(tid >> 4) * 17 + (tid & 15)];
        __threadfence();    // per-thread: drain own stores to coherence point
        __syncthreads();    // all stores in this block now globally visible
        if (tid == 0) {
            const uint32_t prev = atomicAdd(bar, 1u);  // device-scope
            if (prev == (uint32_t)(NPACK - 1)) atomicAdd(bar + 1, 1u);
        }
    }

    // ---- wait: relaxed atomic-RMW poll (no cache maintenance per poll) ----
    if (tid == 0) {
        while (atomicAdd(bar + 1, 0u) == 0u) __builtin_amdgcn_s_sleep(8);
    }
    __syncthreads();
    __threadfence();   // one-time: invalidate stale lines before xpT reads

    // ---- phase 2: gathers + MFMA loop (R10 structure) ----
    const uint2 g0 = *(const uint2*)&xpT[(size_t)j0g * 16 + w0 + lg * 2];
    const uint2 g1 = *(const uint2*)&xpT[(size_t)j1g * 16 + w0 + lg * 2];

    const f16x4 aA = {(f16)a0, (f16)a1, (f16)a2, (f16)a3};
    const f16x4 aB = {(f16)a4, (f16)a5, (f16)a6, (f16)a7};
    const f32x4 cinit0 = {b1v0.x, b1v0.y, b1v0.z, b1v0.w};
    const f32x4 cinit1 = {b1v1.x, b1v1.y, b1v1.z, b1v1.w};

#pragma unroll
    for (int ni = 0; ni < 2; ++ni) {
        const uint2 g = ni ? g1 : g0;
        const f16x4 a = ni ? aB : aA;
        const f32x4 cinit = ni ? cinit1 : cinit0;
        const float4 w2v = ni ? w2v1 : w2v0;
        const float b2n  = ni ? b2n1 : b2n0;
        const int nloc = wv * 2 + ni;

        // stage this ni's sign words (wave-private, lgkmcnt-ordered)
        wbuf[wv][(2 * lg) * 20 + l15]     = g.x;
        wbuf[wv][(2 * lg + 1) * 20 + l15] = g.y;

#pragma unroll
        for (int g4 = 0; g4 < 4; ++g4) {   // 4 groups x 4 tiles of 16 b
#pragma unroll
            for (int t = 0; t < 4; ++t) {
                const int tb = g4 * 4 + t;
                const int wg = tb >> 1;
                const uint4 wk = *(const uint4*)&wbuf[wv][wg * 20 + lg * 4];
                const int pos = (tb & 1) * 16 + l15;
                // bit=1 -> +1.0f16 (0x3C00), bit=0 -> -1.0f16 (0xBC00)
                const uint32_t d0 = 0xBC00BC00u ^ (((wk.x >> pos) & 1u) << 15) ^
                                    ((wk.y >> pos) << 31);
                const uint32_t d1 = 0xBC00BC00u ^ (((wk.z >> pos) & 1u) << 15) ^
                                    ((wk.w >> pos) << 31);
                uint2 bdu; bdu.x = d0; bdu.y = d1;
                const f16x4 bfr = __builtin_bit_cast(f16x4, bdu);

                const f32x4 acc = __builtin_amdgcn_mfma_f32_16x16x16f16(
                    a, bfr, cinit, 0, 0, 0);

                const float zp =
                    fmaf(fmaxf(acc[0], 0.f), w2v.x,
                    fmaf(fmaxf(acc[1], 0.f), w2v.y,
                    fmaf(fmaxf(acc[2], 0.f), w2v.z,
                         fmaxf(acc[3], 0.f) * w2v.w)));
                zbuf[wv][t * 16 + l15][lg] = zp;
            }
            // dense pass: 64 lanes = 64 outputs of this 4-tile group
            const float z = (zbuf[wv][l][0] + zbuf[wv][l][1]) +
                            (zbuf[wv][l][2] + zbuf[wv][l][3]) + b2n;
            const float r = __builtin_amdgcn_rcpf(1.0f + __expf(-z));
            tile[(g4 * 64 + l) * 20 + nloc] = r;
        }
    }
    __syncthreads();

    // full-line stores: 4 lanes cover one 64B row of out[b][n0..n0+15]
#pragma unroll
    for (int p = 0; p < 2; ++p) {
        const int row = (tid >> 2) + p * 128;
        const int c   = (tid & 3) * 4;
        const float4 v = *(const float4*)&tile[row * 20 + c];
        *(float4*)(out + (size_t)(b0 + row) * NN + n0 + c) = v;
    }
}

// ===========================================================================
// Fallback path (R10): separate pack + mfma kernels (used only if the
// cooperative launch is rejected).  Identical math.
// ===========================================================================
__global__ __launch_bounds__(512) void pack_kernel(const float* __restrict__ x,
                                                   uint32_t* __restrict__ xpT) {
    __shared__ uint32_t pstage[32 * 17];
    const int tid = threadIdx.x;
    const int j0  = blockIdx.x * 32;
    const int jl  = tid & 31;
    const int wq  = tid >> 5;
    uint32_t word = 0u;
#pragma unroll
    for (int i = 0; i < 32; ++i)
        word |= (x[(size_t)(wq * 32 + i) * NN + j0 + jl] > 0.0f ? 1u : 0u) << i;
    pstage[jl * 17 + wq] = word;
    __syncthreads();
    xpT[(size_t)j0 * 16 + tid] = pstage[(tid >> 4) * 17 + (tid & 15)];
}

__global__ __launch_bounds__(512, 8) void mfma_kernel(
    const uint32_t* __restrict__ xpT, const float* __restrict__ W1,
    const int* __restrict__ neighs, const float* __restrict__ b1,
    const float* __restrict__ W2, const float* __restrict__ b2,
    float* __restrict__ out) {
    __shared__ __align__(16) uint32_t wbuf[8][8 * 20];
    __shared__ __align__(16) float zbuf[8][64][6];
    __shared__ __align__(16) float tile[256 * 12];

    const int tid = threadIdx.x;
    const int wv  = tid >> 6;
    const int l   = tid & 63;
    const int l15 = l & 15;
    const int lg  = l >> 4;
    const int n0  = blockIdx.x * 8;
    const int b0  = blockIdx.y * 256;
    const int w0  = blockIdx.y * 8;
    const int n   = n0 + wv;

    const int j = neighs[n * KK + l15];
    const uint2 g = *(const uint2*)&xpT[(size_t)j * 16 + w0 + lg * 2];
    const float* W1n = W1 + (size_t)n * (KK * HH) + lg * 4 * HH + l15;
    const float a0 = W1n[0 * HH], a1 = W1n[1 * HH];
    const float a2 = W1n[2 * HH], a3 = W1n[3 * HH];
    const float4 b1v = *(const float4*)(b1 + (size_t)n * HH + lg * 4);
    const float4 w2v = *(const float4*)(W2 + (size_t)n * HH + lg * 4);
    const float b2n = b2[n];

    const f16x4 a = {(f16)a0, (f16)a1, (f16)a2, (f16)a3};
    const f32x4 cinit = {b1v.x, b1v.y, b1v.z, b1v.w};

    wbuf[wv][(2 * lg) * 20 + l15]     = g.x;
    wbuf[wv][(2 * lg + 1) * 20 + l15] = g.y;

#pragma unroll
    for (int g4 = 0; g4 < 4; ++g4) {
#pragma unroll
        for (int t = 0; t < 4; ++t) {
            const int tb = g4 * 4 + t;
            const int wg = tb >> 1;
            const uint4 wk = *(const uint4*)&wbuf[wv][wg * 20 + lg * 4];
            const int pos = (tb & 1) * 16 + l15;
            const uint32_t d0 = 0xBC00BC00u ^ (((wk.x >> pos) & 1u) << 15) ^
                                ((wk.y >> pos) << 31);
            const uint32_t d1 = 0xBC00BC00u ^ (((wk.z >> pos) & 1u) << 15) ^
                                ((wk.w >> pos) << 31);
            uint2 bdu; bdu.x = d0; bdu.y = d1;
            const f16x4 bfr = __builtin_bit_cast(f16x4, bdu);
            const f32x4 acc = __builtin_amdgcn_mfma_f32_16x16x16f16(
                a, bfr, cinit, 0, 0, 0);
            const float zp =
                fmaf(fmaxf(acc[0], 0.f), w2v.x,
                fmaf(fmaxf(acc[1], 0.f), w2v.y,
                fmaf(fmaxf(acc[2], 0.f), w2v.z,
                     fmaxf(acc[3], 0.f) * w2v.w)));
            zbuf[wv][t * 16 + l15][lg] = zp;
        }
        const float z = (zbuf[wv][l][0] + zbuf[wv][l][1]) +
                        (zbuf[wv][l][2] + zbuf[wv][l][3]) + b2n;
        const float r = __builtin_amdgcn_rcpf(1.0f + __expf(-z));
        tile[(g4 * 64 + l) * 12 + wv] = r;
    }
    __syncthreads();

    const int row = tid >> 1;
    const int c   = (tid & 1) * 4;
    const float4 v = *(const float4*)&tile[row * 12 + c];
    *(float4*)(out + (size_t)(b0 + row) * NN + n0 + c) = v;
}

__global__ __launch_bounds__(512) void scalar_kernel(
    const float* __restrict__ x, const int* __restrict__ neighs,
    const float* __restrict__ W1, const float* __restrict__ b1,
    const float* __restrict__ W2, const float* __restrict__ b2,
    float* __restrict__ outp) {
    const int n = blockIdx.x;
    const int b = threadIdx.x;
    const int* nb = neighs + n * KK;
    const float* W1n = W1 + (size_t)n * KK * HH;
    const float* b1n = b1 + (size_t)n * HH;
    const float* W2n = W2 + (size_t)n * HH;

    float s[KK];
#pragma unroll
    for (int k = 0; k < KK; ++k) s[k] = x[(size_t)b * NN + nb[k]];

    float acc[HH];
#pragma unroll
    for (int h = 0; h < HH; ++h) acc[h] = b1n[h];
#pragma unroll
    for (int k = 0; k < KK; ++k)
#pragma unroll
        for (int h = 0; h < HH; ++h)
            acc[h] = fmaf(s[k], W1n[k * HH + h], acc[h]);

    float z = b2[n];
#pragma unroll
    for (int h = 0; h < HH; ++h)
        z = fmaf(fmaxf(acc[h], 0.0f), W2n[h], z);
    outp[(size_t)b * NN + n] = 1.0f / (1.0f + __expf(-z));
}

extern "C" void kernel_launch(void* const* d_in, const int* in_sizes, int n_in,
                              void* d_out, int out_size, void* d_ws, size_t ws_size,
                              hipStream_t stream) {
    const float* x      = (const float*)d_in[0];
    const int*   neighs = (const int*)d_in[1];
    const float* W1     = (const float*)d_in[2];
    const float* b1     = (const float*)d_in[3];
    const float* W2     = (const float*)d_in[4];
    const float* b2     = (const float*)d_in[5];
    float* out = (float*)d_out;

    const size_t pack_bytes = (size_t)NN * 16 * sizeof(uint32_t);  // 512 KB

    if (ws_size >= pack_bytes + 64) {
        uint32_t* xpT = (uint32_t*)d_ws;
        uint32_t* bar = (uint32_t*)((char*)d_ws + pack_bytes);  // 2 words

        hipMemsetAsync(bar, 0, 8, stream);
        void* kargs[] = {(void*)&x, (void*)&neighs, (void*)&W1, (void*)&b1,
                         (void*)&W2, (void*)&b2, (void*)&xpT, (void*)&bar,
                         (void*)&out};
        hipError_t e = hipLaunchCooperativeKernel(
            (const void*)fused_kernel, dim3(NBLK), dim3(512), kargs, 0, stream);
        if (e != hipSuccess) {
            pack_kernel<<<NN / 32, 512, 0, stream>>>(x, xpT);
            mfma_kernel<<<dim3(NN / 8, BB / 256), 512, 0, stream>>>(
                xpT, W1, neighs, b1, W2, b2, out);
        }
    } else {
        scalar_kernel<<<NN, BB, 0, stream>>>(x, neighs, W1, b1, W2, b2, out);
    }
}

// Round 15
// 26.207 us; speedup vs baseline: 16.1689x; 8.1648x over previous
//
#include <hip/hip_runtime.h>
#include <stdint.h>

#define BB 512
#define NN 8192
#define KK 16
#define HH 16

typedef _Float16 f16;
typedef _Float16 f16x4 __attribute__((ext_vector_type(4)));
typedef float f32x4 __attribute__((ext_vector_type(4)));

// ---------------------------------------------------------------------------
// Kernel 1: pack signs of x (+-1) into transposed-word bitmask.
// xpT[j*16+w] bit i = (x[(w*32+i)*N+j] > 0).  512 KB, MALL-resident.
// 256 blocks x 512 thr: coalesced x reads, LDS-staged contiguous 2KB write.
// ---------------------------------------------------------------------------
__global__ __launch_bounds__(512) void pack_kernel(const float* __restrict__ x,
                                                   uint32_t* __restrict__ xpT) {
    __shared__ uint32_t pstage[32 * 17];
    const int tid = threadIdx.x;
    const int j0  = blockIdx.x * 32;
    const int jl  = tid & 31;   // 32 consecutive j -> 128B coalesced reads
    const int wq  = tid >> 5;   // word group 0..15
    uint32_t word = 0u;
#pragma unroll
    for (int i = 0; i < 32; ++i)
        word |= (x[(size_t)(wq * 32 + i) * NN + j0 + jl] > 0.0f ? 1u : 0u) << i;
    pstage[jl * 17 + wq] = word;
    __syncthreads();
    xpT[(size_t)j0 * 16 + tid] = pstage[(tid >> 4) * 17 + (tid & 15)];
}

// ---------------------------------------------------------------------------
// Kernel 2: grid 1024 blocks = EXACTLY one generation at 4 blocks/CU.
// Block = 8n x 512b (full b-span), 512 thr = 8 waves; wave = 1 n.
// Per wave: ONE dwordx4 xpT gather (4 lanes = one whole 64B j-row),
// wbuf layout [w][k] (reads are 4-address broadcast, conflict-free);
// A-frag = 4 strided W1 loads + cvt (R10-proven layout); B-frag = bit ->
// +-1.0f16 via shift/xor into 0xBC00BC00; mfma_f32_16x16x16_f16 (K=16).
// 32 tiles per wave in two halves of 16; per 4-tile group: 8-op relu-dot
// -> zbuf (rows padded to 6 floats, conflict-free), one dense pass
// (64 lanes = 64 outputs, rcpf(1+expf)).  Each half's results land in a
// 12 KB tile, stored as 32B row segments (transpose fused).
// LDS: wbuf 8K + zbuf 12K + tile 12K = 32KB -> 4 blocks/CU, 8 waves/SIMD,
// single generation (no second prologue ramp).
// ---------------------------------------------------------------------------
__global__ __launch_bounds__(512, 8) void mfma_kernel(
    const uint32_t* __restrict__ xpT, const float* __restrict__ W1,
    const int* __restrict__ neighs, const float* __restrict__ b1,
    const float* __restrict__ W2, const float* __restrict__ b2,
    float* __restrict__ out) {
    __shared__ __align__(16) uint32_t wbuf[8][16][16];  // [wave][w][k]
    __shared__ __align__(16) float zbuf[8][64][6];      // padded rows
    __shared__ __align__(16) float tile[256][12];       // half-span transpose

    const int tid = threadIdx.x;
    const int wv  = tid >> 6;        // 0..7  (= n_local)
    const int l   = tid & 63;
    const int l15 = l & 15;
    const int lg  = l >> 4;          // 0..3
    const int n0  = blockIdx.x * 8;
    const int n   = n0 + wv;

    // ---- issue all independent global loads up front (no barriers) ----
    const int j = neighs[n * KK + l15];                  // 64B broadcast
    const uint4 g = *(const uint4*)&xpT[(size_t)j * 16 + lg * 4];
    const float* W1n = W1 + (size_t)n * (KK * HH) + lg * 4 * HH + l15;
    const float a0 = W1n[0 * HH];
    const float a1 = W1n[1 * HH];
    const float a2 = W1n[2 * HH];
    const float a3 = W1n[3 * HH];
    const float4 b1v = *(const float4*)(b1 + (size_t)n * HH + lg * 4);
    const float4 w2v = *(const float4*)(W2 + (size_t)n * HH + lg * 4);
    const float b2n = b2[n];

    const f16x4 a = {(f16)a0, (f16)a1, (f16)a2, (f16)a3};
    const f32x4 cinit = {b1v.x, b1v.y, b1v.z, b1v.w};

    // ---- stage sign words, [w][k] layout (wave-private, lgkmcnt-ordered) ----
    wbuf[wv][lg * 4 + 0][l15] = g.x;
    wbuf[wv][lg * 4 + 1][l15] = g.y;
    wbuf[wv][lg * 4 + 2][l15] = g.z;
    wbuf[wv][lg * 4 + 3][l15] = g.w;

#pragma unroll
    for (int half = 0; half < 2; ++half) {   // b in [half*256, half*256+256)
#pragma unroll
        for (int g4 = 0; g4 < 4; ++g4) {     // 4 groups x 4 tiles of 16 b
#pragma unroll
            for (int t = 0; t < 4; ++t) {
                const int tb  = half * 16 + g4 * 4 + t;   // 0..31
                const int wg  = tb >> 1;                  // word row 0..15
                const int pos = (tb & 1) * 16 + l15;      // bit within word
                // wk: this lane's 4 k-words for word-row wg (broadcast read)
                const uint4 wk = *(const uint4*)&wbuf[wv][wg][lg * 4];
                // bit=1 -> +1.0f16 (0x3C00), bit=0 -> -1.0f16 (0xBC00)
                const uint32_t d0 = 0xBC00BC00u ^ (((wk.x >> pos) & 1u) << 15) ^
                                    ((wk.y >> pos) << 31);
                const uint32_t d1 = 0xBC00BC00u ^ (((wk.z >> pos) & 1u) << 15) ^
                                    ((wk.w >> pos) << 31);
                uint2 bdu; bdu.x = d0; bdu.y = d1;
                const f16x4 bfr = __builtin_bit_cast(f16x4, bdu);

                const f32x4 acc = __builtin_amdgcn_mfma_f32_16x16x16f16(
                    a, bfr, cinit, 0, 0, 0);

                // relu-dot partial: zp(lg, b = tb*16 + l15)
                const float zp =
                    fmaf(fmaxf(acc[0], 0.f), w2v.x,
                    fmaf(fmaxf(acc[1], 0.f), w2v.y,
                    fmaf(fmaxf(acc[2], 0.f), w2v.z,
                         fmaxf(acc[3], 0.f) * w2v.w)));
                zbuf[wv][t * 16 + l15][lg] = zp;
            }
            // dense pass: 64 lanes = 64 outputs of this 4-tile group
            const float z = (zbuf[wv][l][0] + zbuf[wv][l][1]) +
                            (zbuf[wv][l][2] + zbuf[wv][l][3]) + b2n;
            const float r = __builtin_amdgcn_rcpf(1.0f + __expf(-z));
            tile[g4 * 64 + l][wv] = r;
        }
        __syncthreads();
        // store this half: 2 lanes cover one 32B row segment out[b][n0..n0+7]
        {
            const int row = tid >> 1;
            const int c   = (tid & 1) * 4;
            const float4 v = *(const float4*)&tile[row][c];
            *(float4*)(out + (size_t)(half * 256 + row) * NN + n0 + c) = v;
        }
        __syncthreads();   // tile dead before next half reuses it
    }
}

// ---------------------------------------------------------------------------
// Fallback scalar kernel (only if workspace is too small).
// ---------------------------------------------------------------------------
__global__ __launch_bounds__(512) void scalar_kernel(
    const float* __restrict__ x, const int* __restrict__ neighs,
    const float* __restrict__ W1, const float* __restrict__ b1,
    const float* __restrict__ W2, const float* __restrict__ b2,
    float* __restrict__ outp) {
    const int n = blockIdx.x;
    const int b = threadIdx.x;
    const int* nb = neighs + n * KK;
    const float* W1n = W1 + (size_t)n * KK * HH;
    const float* b1n = b1 + (size_t)n * HH;
    const float* W2n = W2 + (size_t)n * HH;

    float s[KK];
#pragma unroll
    for (int k = 0; k < KK; ++k) s[k] = x[(size_t)b * NN + nb[k]];

    float acc[HH];
#pragma unroll
    for (int h = 0; h < HH; ++h) acc[h] = b1n[h];
#pragma unroll
    for (int k = 0; k < KK; ++k)
#pragma unroll
        for (int h = 0; h < HH; ++h)
            acc[h] = fmaf(s[k], W1n[k * HH + h], acc[h]);

    float z = b2[n];
#pragma unroll
    for (int h = 0; h < HH; ++h)
        z = fmaf(fmaxf(acc[h], 0.0f), W2n[h], z);
    outp[(size_t)b * NN + n] = 1.0f / (1.0f + __expf(-z));
}

extern "C" void kernel_launch(void* const* d_in, const int* in_sizes, int n_in,
                              void* d_out, int out_size, void* d_ws, size_t ws_size,
                              hipStream_t stream) {
    const float* x      = (const float*)d_in[0];
    const int*   neighs = (const int*)d_in[1];
    const float* W1     = (const float*)d_in[2];
    const float* b1     = (const float*)d_in[3];
    const float* W2     = (const float*)d_in[4];
    const float* b2     = (const float*)d_in[5];
    float* out = (float*)d_out;

    const size_t pack_bytes = (size_t)NN * 16 * sizeof(uint32_t);  // 512 KB

    if (ws_size >= pack_bytes) {
        uint32_t* xpT = (uint32_t*)d_ws;
        pack_kernel<<<NN / 32, 512, 0, stream>>>(x, xpT);
        mfma_kernel<<<NN / 8, 512, 0, stream>>>(
            xpT, W1, neighs, b1, W2, b2, out);
    } else {
        scalar_kernel<<<NN, BB, 0, stream>>>(x, neighs, W1, b1, W2, b2, out);
    }
}